// Round 14
// baseline (413.927 us; speedup 1.0000x reference)
//
#include <hip/hip_runtime.h>
#include <math.h>

constexpr int Bn = 4, Cc = 128, On = 128, Hh = 160, Ww = 160, Kk = 9;
constexpr int HW = Hh * Ww;          // 25600

typedef __attribute__((ext_vector_type(8))) short s16x8;
typedef __attribute__((ext_vector_type(4))) float f32x4;
typedef __attribute__((address_space(1))) const unsigned int gu32;
typedef __attribute__((address_space(3))) unsigned int lu32;

__device__ inline float bf2f(short s) {
    union { float f; unsigned u; } v;
    v.u = ((unsigned)(unsigned short)s) << 16;
    return v.f;
}
__device__ inline short f2bf(float f) {
    union { float f; unsigned u; } v;
    v.f = f;
    unsigned r = v.u + 0x7fffu + ((v.u >> 16) & 1u);   // RNE
    return (short)(r >> 16);
}

// ---------------------------------------------------------------------------
// Kernel A1: x (NCHW f32) -> xT (NHWC bf16 hi) + xLo (NHWC bf16 lo).
// ---------------------------------------------------------------------------
__global__ __launch_bounds__(256) void to_nhwc(const float* __restrict__ x,
                                               short* __restrict__ xT,
                                               short* __restrict__ xLo) {
    __shared__ float tile[128][65];
    const int t = threadIdx.x;
    const int p0 = blockIdx.x * 64;
    const int b = blockIdx.y;
#pragma unroll
    for (int i = 0; i < 32; ++i) {
        int c = i * 4 + (t >> 6);
        tile[c][t & 63] = x[((size_t)b * Cc + c) * HW + p0 + (t & 63)];
    }
    __syncthreads();
    const int px = t >> 2, cq = t & 3;
    short* dsth = xT  + ((size_t)(b * HW) + p0 + px) * Cc;
    short* dstl = xLo + ((size_t)(b * HW) + p0 + px) * Cc;
#pragma unroll
    for (int j = 0; j < 8; ++j) {
        int c0 = cq * 4 + j * 16;
        short4 vh, vl;
        float f0 = tile[c0 + 0][px], f1 = tile[c0 + 1][px];
        float f2 = tile[c0 + 2][px], f3 = tile[c0 + 3][px];
        vh.x = f2bf(f0); vh.y = f2bf(f1); vh.z = f2bf(f2); vh.w = f2bf(f3);
        vl.x = f2bf(f0 - bf2f(vh.x));
        vl.y = f2bf(f1 - bf2f(vh.y));
        vl.z = f2bf(f2 - bf2f(vh.z));
        vl.w = f2bf(f3 - bf2f(vh.w));
        *(short4*)(dsth + c0) = vh;
        *(short4*)(dstl + c0) = vl;
    }
}

// ---------------------------------------------------------------------------
// Kernel A2: wt (O,C,3,3) f32 -> wbs[k][swizzled o,c] bf16.
// PRE-SWIZZLED so a LINEAR global_load_lds staging reproduces r13's w_lds
// layout: 16B chunk (o*16+cq) lands at chunk (o*16+cq)^(o&15)  (involution,
// same as r13's WRITEW). B-read addresses in dconv are unchanged.
// ---------------------------------------------------------------------------
__global__ void prep_w(const float* __restrict__ wt, short* __restrict__ wbs) {
    int idx = blockIdx.x * 256 + threadIdx.x;     // K*O*C = 147456
    if (idx >= Kk * On * Cc) return;
    int c = idx & 127;
    int o = (idx >> 7) & 127;
    int k = idx >> 14;
    int cq = c >> 3;                              // 16B chunk within o-row
    int ce = c & 7;                               // element within chunk
    int chunk = ((o << 4) | cq) ^ (o & 15);       // swizzled chunk in k-tile
    wbs[(size_t)k * (On * Cc) + (chunk << 3) + ce] = f2bf(wt[(o * Cc + c) * 9 + k]);
}

// ---------------------------------------------------------------------------
// Kernel A3: offset/mask weights -> wofm_{hi,lo}[k][ch32][c].
// ---------------------------------------------------------------------------
__global__ void prep_wofm(const float* __restrict__ w_off,
                          const float* __restrict__ w_mask,
                          short* __restrict__ wh, short* __restrict__ wl) {
    int idx = blockIdx.x * 256 + threadIdx.x;     // 9*32*128 = 36864
    if (idx >= Kk * 32 * Cc) return;
    int c = idx & 127;
    int ch = (idx >> 7) & 31;
    int k = idx >> 12;
    float v = 0.f;
    if (ch < 18)      v = w_off[(ch * Cc + c) * 9 + k];
    else if (ch < 27) v = w_mask[((ch - 18) * Cc + c) * 9 + k];
    short hi = f2bf(v);
    wh[idx] = hi;
    wl[idx] = f2bf(v - bf2f(hi));
}

// ---------------------------------------------------------------------------
// Kernel B: offset/mask conv via MFMA, hi/lo split. ZERO LDS, zero barriers:
// per-lane A from xT/xLo with clamp + zero-select (bit-identical to the
// r8 staged zero-filled halo; this exact A-path passed in r12 phase 1),
// B single-buffered per tap. __launch_bounds__(256,4) -> 16 waves/CU.
// ---------------------------------------------------------------------------
__global__ __launch_bounds__(256, 4) void offmask_mfma(
    const short* __restrict__ xT, const short* __restrict__ xLo,
    const short* __restrict__ wh, const short* __restrict__ wl,
    const float* __restrict__ b_off, const float* __restrict__ b_mask,
    float* __restrict__ dy_o, float* __restrict__ dx_o, float* __restrict__ mk_o)
{
    const int g = blockIdx.x;
    const int orig = (g & 7) * 200 + (g >> 3);
    const int b  = orig / 400;
    const int rem = orig % 400;
    const int h0 = (rem / 10) * 4;
    const int w0 = (rem % 10) * 16;

    const int t = threadIdx.x;
    const int lane = t & 63, wid = t >> 6;
    const int i16 = lane & 15;
    const int kb = (lane >> 4) * 8;

    const int h = h0 + wid;              // wave-uniform row
    const int w = w0 + i16;              // lane's column

    const short* xh_b = xT  + (size_t)b * HW * Cc + kb;
    const short* xl_b = xLo + (size_t)b * HW * Cc + kb;

    const s16x8 vz = {0, 0, 0, 0, 0, 0, 0, 0};

    f32x4 acc[2];
    acc[0] = (f32x4){0.f, 0.f, 0.f, 0.f};
    acc[1] = (f32x4){0.f, 0.f, 0.f, 0.f};

#pragma unroll
    for (int k = 0; k < Kk; ++k) {
        const int r  = h + (k / 3) - 1;
        const int cl = w + (k % 3) - 1;
        const bool ok = ((unsigned)r < (unsigned)Hh) && ((unsigned)cl < (unsigned)Ww);
        const int rc = min(max(r, 0), Hh - 1) * Ww + min(max(cl, 0), Ww - 1);
        const short* pa  = xh_b + (size_t)rc * Cc;
        const short* pl2 = xl_b + (size_t)rc * Cc;
        s16x8 ah[4], al[4];
#pragma unroll
        for (int kk = 0; kk < 4; ++kk) {
            ah[kk] = *(const s16x8*)(pa + kk * 32);
            al[kk] = *(const s16x8*)(pl2 + kk * 32);
        }
        if (!ok) {
#pragma unroll
            for (int kk = 0; kk < 4; ++kk) { ah[kk] = vz; al[kk] = vz; }
        }
#pragma unroll
        for (int tile = 0; tile < 2; ++tile) {
            const short* bp = wh + ((size_t)(k * 32 + tile * 16 + i16)) * Cc + kb;
            const short* lp = wl + ((size_t)(k * 32 + tile * 16 + i16)) * Cc + kb;
            s16x8 bh[4], bl[4];
#pragma unroll
            for (int kk = 0; kk < 4; ++kk) {
                bh[kk] = *(const s16x8*)(bp + kk * 32);
                bl[kk] = *(const s16x8*)(lp + kk * 32);
            }
#pragma unroll
            for (int kk = 0; kk < 4; ++kk) {
                acc[tile] = __builtin_amdgcn_mfma_f32_16x16x32_bf16(ah[kk], bh[kk], acc[tile], 0, 0, 0);
                acc[tile] = __builtin_amdgcn_mfma_f32_16x16x32_bf16(al[kk], bh[kk], acc[tile], 0, 0, 0);
                acc[tile] = __builtin_amdgcn_mfma_f32_16x16x32_bf16(ah[kk], bl[kk], acc[tile], 0, 0, 0);
            }
        }
    }

    // ---- epilogue: D col=lane&15 -> ch, row=(lane>>4)*4+reg -> px ----
#pragma unroll
    for (int tile = 0; tile < 2; ++tile) {
        int ch = tile * 16 + i16;
#pragma unroll
        for (int reg = 0; reg < 4; ++reg) {
            int pxo = (lane >> 4) * 4 + reg;
            int p = h * Ww + w0 + pxo;
            float v = acc[tile][reg];
            if (ch < 18) {
                int k = ch >> 1;
                v += b_off[ch];
                if (ch & 1) dx_o[(size_t)(b * 9 + k) * HW + p] = v;
                else        dy_o[(size_t)(b * 9 + k) * HW + p] = v;
            } else if (ch < 27) {
                int k = ch - 18;
                v += b_mask[k];
                mk_o[(size_t)(b * 9 + k) * HW + p] = 1.f / (1.f + expf(-v));
            }
        }
    }
}

// ---------------------------------------------------------------------------
// Kernel C: main deformable conv. Occupancy edit: SINGLE 32 KB w_lds staged
// via global_load_lds(16B) from pre-swizzled wbs; 2 barriers/k;
// __launch_bounds__(256,4) -> 4 blocks/CU (16 waves). Per-pixel numerics,
// MFMA sequence, 2-D tile decomposition: identical to r13.
// ---------------------------------------------------------------------------
__global__ __launch_bounds__(256, 4) void dconv_main(
    const short* __restrict__ xT,    // [b][hw][c] bf16
    const short* __restrict__ wbs,   // [k][swizzled o,c] bf16
    const float* __restrict__ bias,
    const float* __restrict__ dy_i, const float* __restrict__ dx_i,
    const float* __restrict__ mk_i,
    float* __restrict__ out)
{
    __shared__ short w_lds[128 * 128];   // 32 KB, content swizzled (o&15)<<4

    const int g = blockIdx.x;
    const int orig = (g & 7) * 200 + (g >> 3);
    const int b = orig / 400;
    const int rem = orig % 400;
    const int h0 = (rem / 10) * 4;
    const int w0 = (rem % 10) * 16;

    const int t = threadIdx.x;
    const int lane = t & 63;
    const int wid = t >> 6;
    const int i16 = lane & 15;
    const int h = h0 + wid;
    const int w = w0 + i16;
    const int p = h * Ww + w;
    const int kb8 = (lane >> 4) * 8;

    const short* xbase = xT + (size_t)b * HW * Cc + kb8;

    f32x4 acc[8];
#pragma unroll
    for (int i = 0; i < 8; ++i) acc[i] = (f32x4){0.f, 0.f, 0.f, 0.f};

    float wg[4];
    int   idxc[4];
    s16x8 G[16];

#define SETUPK(kq)                                                             \
    {                                                                          \
        size_t ob = (size_t)(b * 9 + (kq)) * HW + p;                           \
        float dyv = dy_i[ob], dxv = dx_i[ob], mv = mk_i[ob];                   \
        float py  = (float)(h + ((kq) / 3) - 1) + dyv;                         \
        float pxf = (float)(w + ((kq) % 3) - 1) + dxv;                         \
        float y0f = floorf(py), x0f = floorf(pxf);                             \
        float ly = py - y0f, lx = pxf - x0f;                                   \
        int y0 = (int)y0f, x0 = (int)x0f;                                      \
        _Pragma("unroll")                                                      \
        for (int cr = 0; cr < 4; ++cr) {                                       \
            int iy = y0 + (cr >> 1), ix = x0 + (cr & 1);                       \
            bool ok = ((unsigned)iy < (unsigned)Hh) && ((unsigned)ix < (unsigned)Ww); \
            float wy = (cr >> 1) ? ly : (1.f - ly);                            \
            float wx = (cr & 1) ? lx : (1.f - lx);                             \
            int cy = min(max(iy, 0), Hh - 1);                                  \
            int cx = min(max(ix, 0), Ww - 1);                                  \
            idxc[cr] = cy * Ww + cx;                                           \
            wg[cr] = ok ? (wy * wx * mv) : 0.f;                                \
        }                                                                      \
    }

#define ISSUEG                                                                 \
    {                                                                          \
        _Pragma("unroll")                                                      \
        for (int cr = 0; cr < 4; ++cr) {                                       \
            const short* src = xbase + (size_t)idxc[cr] * Cc;                  \
            _Pragma("unroll")                                                  \
            for (int kk = 0; kk < 4; ++kk)                                     \
                G[cr * 4 + kk] = *(const s16x8*)(src + kk * 32);               \
        }                                                                      \
    }

#define STAGE(kq)                                                              \
    {                                                                          \
        const short* gsrc = wbs + (size_t)(kq) * (On * Cc);                    \
        _Pragma("unroll")                                                      \
        for (int i2 = 0; i2 < 8; ++i2) {                                       \
            int chunk = i2 * 256 + t;                                          \
            __builtin_amdgcn_global_load_lds(                                  \
                (gu32*)(gsrc + chunk * 8),                                     \
                (lu32*)((char*)w_lds + chunk * 16),                            \
                16, 0, 0);                                                     \
        }                                                                      \
    }

    // ---- prologue: stage w(0) async + setup/gathers(0); one drain ----
    STAGE(0);
    SETUPK(0);
    ISSUEG;
    __syncthreads();   // vmcnt(0): stage(0) + G(0) landed, LDS visible

#pragma unroll
    for (int k = 0; k < Kk; ++k) {
        // ---- blend(k): G and wg for tap k (landed at last barrier) ----
        s16x8 afr[4];
#pragma unroll
        for (int kk = 0; kk < 4; ++kk) {
#pragma unroll
            for (int j = 0; j < 8; ++j) {
                float sv = wg[0] * bf2f(G[0 * 4 + kk][j])
                         + wg[1] * bf2f(G[1 * 4 + kk][j])
                         + wg[2] * bf2f(G[2 * 4 + kk][j])
                         + wg[3] * bf2f(G[3 * 4 + kk][j]);
                afr[kk][j] = f2bf(sv);
            }
        }

        // ---- MFMA(k): A in regs, B from w_lds (swizzled (o&15)<<4) ----
        {
            const int orow = lane & 15;
#pragma unroll
            for (int ot = 0; ot < 8; ++ot) {
                int o = ot * 16 + orow;
#pragma unroll
                for (int kk = 0; kk < 4; ++kk) {
                    int byte = (o * 256 + (kk * 32 + kb8) * 2) ^ ((o & 15) << 4);
                    s16x8 bfr = *(const s16x8*)((char*)w_lds + byte);
                    acc[ot] = __builtin_amdgcn_mfma_f32_16x16x32_bf16(afr[kk], bfr, acc[ot], 0, 0, 0);
                }
            }
        }

        if (k < Kk - 1) {
            __syncthreads();          // A: all w_lds reads of tap k done
            STAGE(k + 1);             // async glds into the single buffer
            SETUPK(k + 1);
            ISSUEG;
            __syncthreads();          // B: vmcnt(0) -> stage+G landed, visible
        }
    }

#undef SETUPK
#undef ISSUEG
#undef STAGE

    // ---- epilogue: D col=lane&15 (o), row=(lane>>4)*4+reg (px) ----
#pragma unroll
    for (int ot = 0; ot < 8; ++ot) {
        int o = ot * 16 + (lane & 15);
        float bo = bias[o];
        float4 r;
        r.x = acc[ot][0] + bo;
        r.y = acc[ot][1] + bo;
        r.z = acc[ot][2] + bo;
        r.w = acc[ot][3] + bo;
        *(float4*)(out + ((size_t)(b * On + o)) * HW + h * Ww + w0 + (lane >> 4) * 4) = r;
    }
}

// ---------------------------------------------------------------------------
extern "C" void kernel_launch(void* const* d_in, const int* in_sizes, int n_in,
                              void* d_out, int out_size, void* d_ws, size_t ws_size,
                              hipStream_t stream) {
    const float* x      = (const float*)d_in[0];
    const float* w_off  = (const float*)d_in[1];
    const float* b_off  = (const float*)d_in[2];
    const float* w_mask = (const float*)d_in[3];
    const float* b_mask = (const float*)d_in[4];
    const float* wt     = (const float*)d_in[5];
    const float* bias   = (const float*)d_in[6];
    float* out = (float*)d_out;

    short* xT  = (short*)d_ws;                      // B*HW*C bf16 hi
    short* xLo = xT + (size_t)Bn * HW * Cc;         // B*HW*C bf16 lo
    short* wbs = xLo + (size_t)Bn * HW * Cc;        // K*O*C bf16 (swizzled)
    short* wofm_h = wbs + Kk * On * Cc;
    short* wofm_l = wofm_h + Kk * 32 * Cc;
    float* dy = (float*)(wofm_l + Kk * 32 * Cc);
    float* dx = dy + (size_t)Bn * 9 * HW;
    float* mk = dx + (size_t)Bn * 9 * HW;

    to_nhwc<<<dim3(HW / 64, Bn), 256, 0, stream>>>(x, xT, xLo);
    prep_w<<<(Kk * On * Cc + 255) / 256, 256, 0, stream>>>(wt, wbs);
    prep_wofm<<<(Kk * 32 * Cc + 255) / 256, 256, 0, stream>>>(w_off, w_mask, wofm_h, wofm_l);
    offmask_mfma<<<1600, 256, 0, stream>>>(
        xT, xLo, wofm_h, wofm_l, b_off, b_mask, dy, dx, mk);
    dconv_main<<<1600, 256, 0, stream>>>(
        xT, wbs, bias, dy, dx, mk, out);
}